// Round 14
// baseline (222.687 us; speedup 1.0000x reference)
//
#include <hip/hip_runtime.h>
#include <hip/hip_bf16.h>
#include <stdint.h>

// Problem constants: B=2, S=2048, H=2048, NH=32, HD=64
#define S_LEN 2048
#define NHEAD 32
#define HDIM  64

using bf16x8 = __attribute__((ext_vector_type(8))) short;
using f32x4  = __attribute__((ext_vector_type(4))) float;
using f32x16 = __attribute__((ext_vector_type(16))) float;

__device__ __forceinline__ uint16_t f2bf(float f) {
  union { float f; uint32_t u; } c; c.f = f;
  uint32_t u = c.u;
  return (uint16_t)((u + 0x7FFFu + ((u >> 16) & 1u)) >> 16);
}

__device__ __forceinline__ void load_lds16(const void* g, void* l) {
  __builtin_amdgcn_global_load_lds(
      (const __attribute__((address_space(1))) void*)g,
      (__attribute__((address_space(3))) void*)l, 16, 0, 0);
}

__device__ __forceinline__ f32x16 mfma32(bf16x8 a, bf16x8 b, f32x16 c) {
  return __builtin_amdgcn_mfma_f32_32x32x16_bf16(a, b, c, 0, 0, 0);
}

__device__ __forceinline__ uint32_t cvtpk(float lo, float hi_) {
  uint32_t d;
  asm("v_cvt_pk_bf16_f32 %0, %1, %2" : "=v"(d) : "v"(lo), "v"(hi_));
  return d;
}
__device__ __forceinline__ void plswap(uint32_t& a, uint32_t& b) {
  asm volatile("v_permlane32_swap_b32 %0, %1" : "+v"(a), "+v"(b));
}
// 2^x directly (Q pre-scaled by log2e so 2^s == e^{s_true})
__device__ __forceinline__ float exp2_hw(float x) {
  float r;
  asm("v_exp_f32 %0, %1" : "=v"(r) : "v"(x));
  return r;
}

// ---------------- batched fp32 -> bf16 conversion (X + all 4 weights) -----
__global__ __launch_bounds__(256) void conv_batch(
    const float* __restrict__ X, const float* __restrict__ Wq,
    const float* __restrict__ Wk, const float* __restrict__ Wv,
    const float* __restrict__ Wo, uint16_t* __restrict__ Xbf,
    uint16_t* __restrict__ Wqk, uint16_t* __restrict__ Wvb,
    uint16_t* __restrict__ Wob) {
  int i = blockIdx.x * 256 + threadIdx.x;  // total 6291456
  const float* src; uint16_t* dst; int o;
  if (i < 2097152)      { src = X;  dst = Xbf;           o = i; }
  else if (i < 3145728) { src = Wq; dst = Wqk;           o = i - 2097152; }
  else if (i < 4194304) { src = Wk; dst = Wqk + 4194304; o = i - 3145728; }
  else if (i < 5242880) { src = Wv; dst = Wvb;           o = i - 4194304; }
  else                  { src = Wo; dst = Wob;           o = i - 5242880; }
  float4 v = ((const float4*)src)[o];
  uint64_t packed = (uint64_t)f2bf(v.x) | ((uint64_t)f2bf(v.y) << 16) |
                    ((uint64_t)f2bf(v.z) << 32) | ((uint64_t)f2bf(v.w) << 48);
  ((uint64_t*)dst)[o] = packed;
}

// ---------------- fused QK GEMM: 256x256, BK=32, 3-buf, 2-phase/tile ------
// (r6 — best measured 71.5 us / MfmaUtil ~39; family plateau ~950 TF)
__global__ __launch_bounds__(512, 2) void gemm_qk(
    const uint16_t* __restrict__ A, const uint16_t* __restrict__ Bw,
    uint16_t* __restrict__ Qo, uint16_t* __restrict__ Ko, float qscale) {
  extern __shared__ char smem[];  // 3 * 32768
  const int t = threadIdx.x;
  const int lane = t & 63, w = t >> 6;
  const int lrow = lane & 15, lgrp = lane >> 4;
  const int wr = w >> 2, wc = w & 3;
  const int id = blockIdx.x;
  const int swz = (id & 7) * 32 + (id >> 3);
  const int bm = (swz & 15) * 256, bn = (swz >> 4) * 256;
  constexpr int NT = 2048 / 32;

  const f32x4 zero4 = {0.f, 0.f, 0.f, 0.f};
  f32x4 acc[8][4];
#pragma unroll
  for (int mi = 0; mi < 8; ++mi)
#pragma unroll
    for (int ni = 0; ni < 4; ++ni) acc[mi][ni] = zero4;

  auto stage_mat = [&](const uint16_t* __restrict__ G, int grow0,
                       char* ldsbase, int kt) {
#pragma unroll
    for (int j = 0; j < 2; ++j) {
      const int s = t + j * 512;
      const int row = s >> 2;
      const int sc = (s & 3) ^ ((row >> 1) & 3);
      load_lds16(G + (size_t)(grow0 + row) * 2048 + kt + sc * 8,
                 ldsbase + j * 8192 + w * 1024);
    }
  };
  auto lda = [&](const char* Ab, int mi) -> bf16x8 {
    const int row = wr * 128 + mi * 16 + lrow;
    return *(const bf16x8*)(Ab + row * 64 + ((lgrp ^ ((row >> 1) & 3)) << 4));
  };
  auto ldb = [&](const char* Bb, int ni) -> bf16x8 {
    const int row = wc * 64 + ni * 16 + lrow;
    return *(const bf16x8*)(Bb + row * 64 + ((lgrp ^ ((row >> 1) & 3)) << 4));
  };

  stage_mat(A, bm, smem, 0);
  stage_mat(Bw, bn, smem + 16384, 0);
  stage_mat(A, bm, smem + 32768, 32);
  stage_mat(Bw, bn, smem + 32768 + 16384, 32);

  for (int kt = 0; kt < NT; ++kt) {
    char* cur = smem + (kt % 3) * 32768;
    char* nx2 = smem + ((kt + 2) % 3) * 32768;
    if (kt < NT - 1) asm volatile("s_waitcnt vmcnt(4)" ::: "memory");
    else             asm volatile("s_waitcnt vmcnt(0)" ::: "memory");
    __builtin_amdgcn_s_barrier();

    bf16x8 aF[4], bF[4];
#pragma unroll
    for (int mi = 0; mi < 4; ++mi) aF[mi] = lda(cur, mi);
#pragma unroll
    for (int ni = 0; ni < 4; ++ni) bF[ni] = ldb(cur + 16384, ni);
    if (kt + 2 < NT) stage_mat(A, bm, nx2, (kt + 2) * 32);
    __builtin_amdgcn_s_barrier();
    asm volatile("s_waitcnt lgkmcnt(0)" ::: "memory");
    __builtin_amdgcn_sched_barrier(0);
    __builtin_amdgcn_s_setprio(1);
#pragma unroll
    for (int mi = 0; mi < 4; ++mi)
#pragma unroll
      for (int ni = 0; ni < 4; ++ni)
        acc[mi][ni] = __builtin_amdgcn_mfma_f32_16x16x32_bf16(
            aF[mi], bF[ni], acc[mi][ni], 0, 0, 0);
    __builtin_amdgcn_s_setprio(0);
    __builtin_amdgcn_s_barrier();

    bf16x8 aG[4];
#pragma unroll
    for (int mi = 0; mi < 4; ++mi) aG[mi] = lda(cur, 4 + mi);
    if (kt + 2 < NT) stage_mat(Bw, bn, nx2 + 16384, (kt + 2) * 32);
    __builtin_amdgcn_s_barrier();
    asm volatile("s_waitcnt lgkmcnt(0)" ::: "memory");
    __builtin_amdgcn_sched_barrier(0);
    __builtin_amdgcn_s_setprio(1);
#pragma unroll
    for (int mi = 0; mi < 4; ++mi)
#pragma unroll
      for (int ni = 0; ni < 4; ++ni)
        acc[4 + mi][ni] = __builtin_amdgcn_mfma_f32_16x16x32_bf16(
            aG[mi], bF[ni], acc[4 + mi][ni], 0, 0, 0);
    __builtin_amdgcn_s_setprio(0);
  }

  const bool isQ = (bn < 2048);
#pragma unroll
  for (int mi = 0; mi < 8; ++mi) {
#pragma unroll
    for (int ni = 0; ni < 4; ++ni) {
      const int n = bn + wc * 64 + ni * 16 + lrow;
      const int n2 = isQ ? n : (n - 2048);
      const int h = n2 >> 6, d = n2 & 63;
#pragma unroll
      for (int r = 0; r < 4; ++r) {
        const int m = bm + wr * 128 + mi * 16 + lgrp * 4 + r;
        const int b = m >> 11, s = m & 2047;
        const size_t off = (((size_t)(b * NHEAD + h) * S_LEN + s) * HDIM) + d;
        if (isQ) Qo[off] = f2bf(acc[mi][ni][r] * qscale);
        else     Ko[off] = f2bf(acc[mi][ni][r]);
      }
    }
  }
}

// ---------------- NT GEMM 128^2, BK=32, 3-buf, 1 barrier/tile (r6) --------
template<int MODE>
__global__ __launch_bounds__(256, 3) void gemm_nt(
    const uint16_t* __restrict__ A, const uint16_t* __restrict__ B,
    void* __restrict__ C, int M, int N, int K, float scale) {
  __shared__ __align__(16) char smem[3][16384];

  const int t = threadIdx.x;
  const int lane = t & 63, w = t >> 6;
  const int lrow = lane & 15, lgrp = lane >> 4;
  const int bm = blockIdx.y * 128, bn = blockIdx.x * 128;
  const int wm = (w >> 1) * 64, wn = (w & 1) * 64;
  const int NT = K / 32;

  const f32x4 zero4 = {0.f, 0.f, 0.f, 0.f};
  f32x4 acc[4][4];
#pragma unroll
  for (int mi = 0; mi < 4; ++mi)
#pragma unroll
    for (int ni = 0; ni < 4; ++ni) acc[mi][ni] = zero4;

  auto stage_mat = [&](const uint16_t* __restrict__ G, int grow0,
                       char* ldsbase, int kt) {
#pragma unroll
    for (int j = 0; j < 2; ++j) {
      const int s = t + j * 256;
      const int row = s >> 2;
      const int sc = (s & 3) ^ ((row >> 1) & 3);
      load_lds16(G + (size_t)(grow0 + row) * K + kt + sc * 8,
                 ldsbase + j * 4096 + w * 1024);
    }
  };
  auto ldf = [&](const char* Mb, int base, int i) -> bf16x8 {
    const int row = base + i * 16 + lrow;
    return *(const bf16x8*)(Mb + row * 64 + ((lgrp ^ ((row >> 1) & 3)) << 4));
  };

  stage_mat(A, bm, smem[0], 0);
  stage_mat(B, bn, smem[0] + 8192, 0);
  stage_mat(A, bm, smem[1], 32);
  stage_mat(B, bn, smem[1] + 8192, 32);

  for (int kt = 0; kt < NT; ++kt) {
    char* cur = smem[kt % 3];
    if (kt < NT - 1) asm volatile("s_waitcnt vmcnt(4)" ::: "memory");
    else             asm volatile("s_waitcnt vmcnt(0)" ::: "memory");
    __builtin_amdgcn_s_barrier();

    if (kt + 2 < NT) {
      char* nx2 = smem[(kt + 2) % 3];
      stage_mat(A, bm, nx2, (kt + 2) * 32);
      stage_mat(B, bn, nx2 + 8192, (kt + 2) * 32);
    }

    bf16x8 aF[4], bF[4];
#pragma unroll
    for (int mi = 0; mi < 4; ++mi) aF[mi] = ldf(cur, wm, mi);
#pragma unroll
    for (int ni = 0; ni < 4; ++ni) bF[ni] = ldf(cur + 8192, wn, ni);
#pragma unroll
    for (int mi = 0; mi < 4; ++mi)
#pragma unroll
      for (int ni = 0; ni < 4; ++ni)
        acc[mi][ni] = __builtin_amdgcn_mfma_f32_16x16x32_bf16(
            aF[mi], bF[ni], acc[mi][ni], 0, 0, 0);
  }

#pragma unroll
  for (int mi = 0; mi < 4; ++mi) {
#pragma unroll
    for (int ni = 0; ni < 4; ++ni) {
      const int n = bn + wn + ni * 16 + lrow;
#pragma unroll
      for (int r = 0; r < 4; ++r) {
        const int m = bm + wm + mi * 16 + lgrp * 4 + r;
        const float v = acc[mi][ni][r] * scale;
        if (MODE == 2) {
          ((float*)C)[(size_t)m * N + n] = v;
        } else {
          const int h = m >> 6, d = m & 63;
          const int b = n >> 11, s = n & 2047;
          ((uint16_t*)C)[(((size_t)(b * NHEAD + h) * HDIM + d) * S_LEN) + s] =
              f2bf(v);
        }
      }
    }
  }
}

// ---------------- causal flash attention v6: cross-pass pipeline ----------
// v5 (KVBLK=128, 2 subtiles) + (a) global stage-parity: pass-2 tile-0 is
// staged during pass-1's last tile compute (no inter-pass drain), and
// (b) both subtiles' exp chains run before either repack/PV (parallel
// serial-VALU chains). Denominator on MFMA pipe (oS).
__global__ __launch_bounds__(256, 2) void attn_kernel(
    const uint16_t* __restrict__ Q, const uint16_t* __restrict__ K,
    const uint16_t* __restrict__ Vt, uint16_t* __restrict__ O) {
  extern __shared__ __align__(16) char asmem[];  // 65536
  const int t = threadIdx.x, lane = t & 63, w = t >> 6;
  const int qcol = lane & 31, hi = lane >> 5;
  const int id = blockIdx.x;
  const int bh = (id & 7) * 8 + ((id >> 3) & 7);  // 8 heads per XCD
  const int p = id >> 6;                           // 0..7
  const int b = bh >> 5, h = bh & 31;

  const uint16_t* Qbh = Q + (size_t)bh * S_LEN * HDIM;
  const uint16_t* Kbh = K + (size_t)bh * S_LEN * HDIM;
  const uint16_t* Vbh = Vt + (size_t)bh * HDIM * S_LEN;

  const int srow = lane >> 3;
  const int schunk = (lane & 7) ^ srow;

  const short one_bf = (short)0x3F80;  // bf16 1.0
  const bf16x8 onesf = {one_bf, one_bf, one_bf, one_bf,
                        one_bf, one_bf, one_bf, one_bf};

  auto Kbuf = [&](int bi, int sub) -> char* {
    return asmem + (bi * 2 + sub) * 8192;
  };
  auto Vbuf = [&](int bi, int sub) -> char* {
    return asmem + 32768 + (bi * 2 + sub) * 8192;
  };

  auto stage = [&](int k0, int bi) {
#pragma unroll
    for (int sub = 0; sub < 2; ++sub) {
      const int kb = k0 + sub * 64;
#pragma unroll
      for (int j = 0; j < 2; ++j) {
        const int r = j * 32 + w * 8 + srow;
        load_lds16(Kbh + (size_t)(kb + r) * HDIM + schunk * 8,
                   Kbuf(bi, sub) + j * 4096 + w * 1024);
        load_lds16(Vbh + (size_t)r * S_LEN + kb + schunk * 8,
                   Vbuf(bi, sub) + j * 4096 + w * 1024);
      }
    }
  };

  const int rk0 = qcol, rk1 = 32 + qcol;
  const int x0 = qcol & 7;

  int g = 0;  // global staged-tile counter: buffer parity across passes

  for (int pass = 0; pass < 2; ++pass) {
    const int jq = pass ? (15 - p) : p;        // 128-row q-tile index
    const int qw = jq * 128 + w * 32;
    const int qg = qw + qcol;

    bf16x8 qB[4];
    {
      const uint16_t* qp = Qbh + (size_t)qg * HDIM + hi * 8;
#pragma unroll
      for (int j = 0; j < 4; ++j) qB[j] = *(const bf16x8*)(qp + 16 * j);
    }

    f32x16 oacc0, oacc1, oS;
#pragma unroll
    for (int r = 0; r < 16; ++r) { oacc0[r] = 0.f; oacc1[r] = 0.f; oS[r] = 0.f; }

    auto qk = [&](const char* Kc, f32x16& s0, f32x16& s1) {
#pragma unroll
      for (int r = 0; r < 16; ++r) { s0[r] = 0.f; s1[r] = 0.f; }
      __builtin_amdgcn_s_setprio(1);
#pragma unroll
      for (int j = 0; j < 4; ++j) {
        bf16x8 kf0 = *(const bf16x8*)(Kc + rk0 * 128 + (((2*j+hi) ^ x0) << 4));
        bf16x8 kf1 = *(const bf16x8*)(Kc + rk1 * 128 + (((2*j+hi) ^ x0) << 4));
        s0 = mfma32(kf0, qB[j], s0);
        s1 = mfma32(kf1, qB[j], s1);
      }
      __builtin_amdgcn_s_setprio(0);
    };
    auto smx = [&](int k0s, f32x16& s0, f32x16& s1) {
      if (k0s + 63 > qw) {
#pragma unroll
        for (int r = 0; r < 16; ++r) {
          const int krow = (r & 3) + 8 * (r >> 2) + 4 * hi;
          s0[r] = (k0s + krow <= qg) ? exp2_hw(s0[r]) : 0.f;
          s1[r] = (k0s + 32 + krow <= qg) ? exp2_hw(s1[r]) : 0.f;
        }
      } else {
#pragma unroll
        for (int r = 0; r < 16; ++r) {
          s0[r] = exp2_hw(s0[r]);
          s1[r] = exp2_hw(s1[r]);
        }
      }
    };
    auto repack = [&](const f32x16& s0, const f32x16& s1, bf16x8 (&paf)[4]) {
#pragma unroll
      for (int tt = 0; tt < 4; ++tt) {
        const int o = 8 * (tt & 1);
        uint32_t a0, a1, a2, a3;
        if (tt < 2) {
          a0 = cvtpk(s0[o + 0], s0[o + 1]);
          a1 = cvtpk(s0[o + 2], s0[o + 3]);
          a2 = cvtpk(s0[o + 4], s0[o + 5]);
          a3 = cvtpk(s0[o + 6], s0[o + 7]);
        } else {
          a0 = cvtpk(s1[o + 0], s1[o + 1]);
          a1 = cvtpk(s1[o + 2], s1[o + 3]);
          a2 = cvtpk(s1[o + 4], s1[o + 5]);
          a3 = cvtpk(s1[o + 6], s1[o + 7]);
        }
        plswap(a0, a2);
        plswap(a1, a3);
        union { uint32_t u[4]; bf16x8 v; } pk;
        pk.u[0] = a0; pk.u[1] = a1; pk.u[2] = a2; pk.u[3] = a3;
        paf[tt] = pk.v;
      }
    };
    auto pv = [&](const char* Vc, const bf16x8 (&paf)[4]) {
      __builtin_amdgcn_s_setprio(1);
#pragma unroll
      for (int tt = 0; tt < 4; ++tt) {
        const int c = 2 * tt + hi;
        bf16x8 v0f = *(const bf16x8*)(Vc + rk0 * 128 + ((c ^ x0) << 4));
        bf16x8 v1f = *(const bf16x8*)(Vc + rk1 * 128 + ((c ^ x0) << 4));
        oacc0 = mfma32(paf[tt], v0f, oacc0);
        oacc1 = mfma32(paf[tt], v1f, oacc1);
        oS = mfma32(paf[tt], onesf, oS);
      }
      __builtin_amdgcn_s_setprio(0);
    };

    const int nt = jq + 1;   // 128-wide kv tiles
    for (int kt = 0; kt < nt; ++kt, ++g) {
      const int cur = g & 1;
      const int k0 = kt * 128;
      if (g == 0) stage(0, 0);            // very first stage only
      __syncthreads();                     // stage(g) landed (vmcnt drained)
      if (kt + 1 < nt)       stage((kt + 1) * 128, cur ^ 1);
      else if (pass == 0)    stage(0, cur ^ 1);  // next pass's tile 0

      const bool a1 = (k0 + 64 <= qw + 31);
      f32x16 s0a, s1a, s0b, s1b;
      qk(Kbuf(cur, 0), s0a, s1a);
      if (a1) qk(Kbuf(cur, 1), s0b, s1b);
      smx(k0, s0a, s1a);
      if (a1) smx(k0 + 64, s0b, s1b);      // parallel exp chains
      bf16x8 pafA[4], pafB[4];
      repack(s0a, s1a, pafA);
      pv(Vbuf(cur, 0), pafA);
      if (a1) {
        repack(s0b, s1b, pafB);
        pv(Vbuf(cur, 1), pafB);
      }
    }

#pragma unroll
    for (int r = 0; r < 16; ++r) {
      const int qrow = (r & 3) + 8 * (r >> 2) + 4 * hi;
      const float inv = 1.0f / oS[r];
      const size_t base = ((size_t)b * S_LEN + qw + qrow) * 2048 + h * 64;
      O[base + qcol] = f2bf(oacc0[r] * inv);
      O[base + 32 + qcol] = f2bf(oacc1[r] * inv);
    }
  }
}

// ---------------- launcher ----------------
extern "C" void kernel_launch(void* const* d_in, const int* in_sizes, int n_in,
                              void* d_out, int out_size, void* d_ws,
                              size_t ws_size, hipStream_t stream) {
  const float* X  = (const float*)d_in[0];
  const float* Wq = (const float*)d_in[2];
  const float* Wk = (const float*)d_in[3];
  const float* Wv = (const float*)d_in[4];
  const float* Wo = (const float*)d_in[5];
  float* out = (float*)d_out;

  char* ws = (char*)d_ws;
  uint16_t* Xbf = (uint16_t*)ws;                    // 16.78 MB [4096][2048]
  uint16_t* Wqk = (uint16_t*)(ws + 16777216);       // 16.78 MB [4096][2048]
  uint16_t* Qb  = (uint16_t*)(ws + 33554432);       // 16.78 MB [B,NH,S,HD]
  uint16_t* Kb  = (uint16_t*)(ws + 50331648);       // 16.78 MB [B,NH,S,HD]
  uint16_t* Wsm = (uint16_t*)(ws + 67108864);       //  8.39 MB (Wv bf16)
  uint16_t* Wob = (uint16_t*)(ws + 75497472);       //  8.39 MB (Wo bf16)
  uint16_t* Vtb = Wqk;   // Vt aliases Wqk (dead after QK GEMM)
  uint16_t* Ob  = Xbf;   // O aliases Xbf (dead after Vt GEMM)

  // 1/sqrt(HD) * log2(e): softmax weights computed as 2^s (v_exp_f32 direct)
  const float qscale = 0.125f * 1.4426950408889634f;

  hipFuncSetAttribute((const void*)gemm_qk,
                      hipFuncAttributeMaxDynamicSharedMemorySize, 98304);
  hipFuncSetAttribute((const void*)attn_kernel,
                      hipFuncAttributeMaxDynamicSharedMemorySize, 65536);

  conv_batch<<<24576, 256, 0, stream>>>(X, Wq, Wk, Wv, Wo, Xbf, Wqk, Wsm, Wob);
  gemm_qk<<<256, 512, 98304, stream>>>(Xbf, Wqk, Qb, Kb, qscale);
  gemm_nt<1><<<dim3(32, 16), 256, 0, stream>>>(Wsm, Xbf, Vtb, 2048, 4096, 2048, 1.0f);
  attn_kernel<<<512, 256, 65536, stream>>>(Qb, Kb, Vtb, Ob);
  gemm_nt<2><<<dim3(16, 32), 256, 0, stream>>>(Ob, Wob, out, 4096, 2048, 2048, 1.0f);
}

// Round 15
// 221.976 us; speedup vs baseline: 1.0032x; 1.0032x over previous
//
#include <hip/hip_runtime.h>
#include <hip/hip_bf16.h>
#include <stdint.h>

// Problem constants: B=2, S=2048, H=2048, NH=32, HD=64
#define S_LEN 2048
#define NHEAD 32
#define HDIM  64

using bf16x8 = __attribute__((ext_vector_type(8))) short;
using f32x4  = __attribute__((ext_vector_type(4))) float;
using f32x16 = __attribute__((ext_vector_type(16))) float;

__device__ __forceinline__ uint16_t f2bf(float f) {
  union { float f; uint32_t u; } c; c.f = f;
  uint32_t u = c.u;
  return (uint16_t)((u + 0x7FFFu + ((u >> 16) & 1u)) >> 16);
}

__device__ __forceinline__ void load_lds16(const void* g, void* l) {
  __builtin_amdgcn_global_load_lds(
      (const __attribute__((address_space(1))) void*)g,
      (__attribute__((address_space(3))) void*)l, 16, 0, 0);
}

__device__ __forceinline__ f32x16 mfma32(bf16x8 a, bf16x8 b, f32x16 c) {
  return __builtin_amdgcn_mfma_f32_32x32x16_bf16(a, b, c, 0, 0, 0);
}

__device__ __forceinline__ uint32_t cvtpk(float lo, float hi_) {
  uint32_t d;
  asm("v_cvt_pk_bf16_f32 %0, %1, %2" : "=v"(d) : "v"(lo), "v"(hi_));
  return d;
}
__device__ __forceinline__ void plswap(uint32_t& a, uint32_t& b) {
  asm volatile("v_permlane32_swap_b32 %0, %1" : "+v"(a), "+v"(b));
}
// 2^x directly (Q pre-scaled by log2e so 2^s == e^{s_true})
__device__ __forceinline__ float exp2_hw(float x) {
  float r;
  asm("v_exp_f32 %0, %1" : "=v"(r) : "v"(x));
  return r;
}

// ---------------- batched fp32 -> bf16 conversion (X + all 4 weights) -----
__global__ __launch_bounds__(256) void conv_batch(
    const float* __restrict__ X, const float* __restrict__ Wq,
    const float* __restrict__ Wk, const float* __restrict__ Wv,
    const float* __restrict__ Wo, uint16_t* __restrict__ Xbf,
    uint16_t* __restrict__ Wqk, uint16_t* __restrict__ Wvb,
    uint16_t* __restrict__ Wob) {
  int i = blockIdx.x * 256 + threadIdx.x;  // total 6291456
  const float* src; uint16_t* dst; int o;
  if (i < 2097152)      { src = X;  dst = Xbf;           o = i; }
  else if (i < 3145728) { src = Wq; dst = Wqk;           o = i - 2097152; }
  else if (i < 4194304) { src = Wk; dst = Wqk + 4194304; o = i - 3145728; }
  else if (i < 5242880) { src = Wv; dst = Wvb;           o = i - 4194304; }
  else                  { src = Wo; dst = Wob;           o = i - 5242880; }
  float4 v = ((const float4*)src)[o];
  uint64_t packed = (uint64_t)f2bf(v.x) | ((uint64_t)f2bf(v.y) << 16) |
                    ((uint64_t)f2bf(v.z) << 32) | ((uint64_t)f2bf(v.w) << 48);
  ((uint64_t*)dst)[o] = packed;
}

// ---------------- fused QK GEMM: 256x256, BK=32, 3-buf, 2-phase/tile ------
// (r6 — best measured 71.5 us / MfmaUtil ~39; family plateau ~950 TF)
__global__ __launch_bounds__(512, 2) void gemm_qk(
    const uint16_t* __restrict__ A, const uint16_t* __restrict__ Bw,
    uint16_t* __restrict__ Qo, uint16_t* __restrict__ Ko, float qscale) {
  extern __shared__ char smem[];  // 3 * 32768
  const int t = threadIdx.x;
  const int lane = t & 63, w = t >> 6;
  const int lrow = lane & 15, lgrp = lane >> 4;
  const int wr = w >> 2, wc = w & 3;
  const int id = blockIdx.x;
  const int swz = (id & 7) * 32 + (id >> 3);
  const int bm = (swz & 15) * 256, bn = (swz >> 4) * 256;
  constexpr int NT = 2048 / 32;

  const f32x4 zero4 = {0.f, 0.f, 0.f, 0.f};
  f32x4 acc[8][4];
#pragma unroll
  for (int mi = 0; mi < 8; ++mi)
#pragma unroll
    for (int ni = 0; ni < 4; ++ni) acc[mi][ni] = zero4;

  auto stage_mat = [&](const uint16_t* __restrict__ G, int grow0,
                       char* ldsbase, int kt) {
#pragma unroll
    for (int j = 0; j < 2; ++j) {
      const int s = t + j * 512;
      const int row = s >> 2;
      const int sc = (s & 3) ^ ((row >> 1) & 3);
      load_lds16(G + (size_t)(grow0 + row) * 2048 + kt + sc * 8,
                 ldsbase + j * 8192 + w * 1024);
    }
  };
  auto lda = [&](const char* Ab, int mi) -> bf16x8 {
    const int row = wr * 128 + mi * 16 + lrow;
    return *(const bf16x8*)(Ab + row * 64 + ((lgrp ^ ((row >> 1) & 3)) << 4));
  };
  auto ldb = [&](const char* Bb, int ni) -> bf16x8 {
    const int row = wc * 64 + ni * 16 + lrow;
    return *(const bf16x8*)(Bb + row * 64 + ((lgrp ^ ((row >> 1) & 3)) << 4));
  };

  stage_mat(A, bm, smem, 0);
  stage_mat(Bw, bn, smem + 16384, 0);
  stage_mat(A, bm, smem + 32768, 32);
  stage_mat(Bw, bn, smem + 32768 + 16384, 32);

  for (int kt = 0; kt < NT; ++kt) {
    char* cur = smem + (kt % 3) * 32768;
    char* nx2 = smem + ((kt + 2) % 3) * 32768;
    if (kt < NT - 1) asm volatile("s_waitcnt vmcnt(4)" ::: "memory");
    else             asm volatile("s_waitcnt vmcnt(0)" ::: "memory");
    __builtin_amdgcn_s_barrier();

    bf16x8 aF[4], bF[4];
#pragma unroll
    for (int mi = 0; mi < 4; ++mi) aF[mi] = lda(cur, mi);
#pragma unroll
    for (int ni = 0; ni < 4; ++ni) bF[ni] = ldb(cur + 16384, ni);
    if (kt + 2 < NT) stage_mat(A, bm, nx2, (kt + 2) * 32);
    __builtin_amdgcn_s_barrier();
    asm volatile("s_waitcnt lgkmcnt(0)" ::: "memory");
    __builtin_amdgcn_sched_barrier(0);
    __builtin_amdgcn_s_setprio(1);
#pragma unroll
    for (int mi = 0; mi < 4; ++mi)
#pragma unroll
      for (int ni = 0; ni < 4; ++ni)
        acc[mi][ni] = __builtin_amdgcn_mfma_f32_16x16x32_bf16(
            aF[mi], bF[ni], acc[mi][ni], 0, 0, 0);
    __builtin_amdgcn_s_setprio(0);
    __builtin_amdgcn_s_barrier();

    bf16x8 aG[4];
#pragma unroll
    for (int mi = 0; mi < 4; ++mi) aG[mi] = lda(cur, 4 + mi);
    if (kt + 2 < NT) stage_mat(Bw, bn, nx2 + 16384, (kt + 2) * 32);
    __builtin_amdgcn_s_barrier();
    asm volatile("s_waitcnt lgkmcnt(0)" ::: "memory");
    __builtin_amdgcn_sched_barrier(0);
    __builtin_amdgcn_s_setprio(1);
#pragma unroll
    for (int mi = 0; mi < 4; ++mi)
#pragma unroll
      for (int ni = 0; ni < 4; ++ni)
        acc[4 + mi][ni] = __builtin_amdgcn_mfma_f32_16x16x32_bf16(
            aG[mi], bF[ni], acc[4 + mi][ni], 0, 0, 0);
    __builtin_amdgcn_s_setprio(0);
  }

  const bool isQ = (bn < 2048);
#pragma unroll
  for (int mi = 0; mi < 8; ++mi) {
#pragma unroll
    for (int ni = 0; ni < 4; ++ni) {
      const int n = bn + wc * 64 + ni * 16 + lrow;
      const int n2 = isQ ? n : (n - 2048);
      const int h = n2 >> 6, d = n2 & 63;
#pragma unroll
      for (int r = 0; r < 4; ++r) {
        const int m = bm + wr * 128 + mi * 16 + lgrp * 4 + r;
        const int b = m >> 11, s = m & 2047;
        const size_t off = (((size_t)(b * NHEAD + h) * S_LEN + s) * HDIM) + d;
        if (isQ) Qo[off] = f2bf(acc[mi][ni][r] * qscale);
        else     Ko[off] = f2bf(acc[mi][ni][r]);
      }
    }
  }
}

// ---------------- NT GEMM 128^2, BK=32, 3-buf, 1 barrier/tile (r6) --------
template<int MODE>
__global__ __launch_bounds__(256, 3) void gemm_nt(
    const uint16_t* __restrict__ A, const uint16_t* __restrict__ B,
    void* __restrict__ C, int M, int N, int K, float scale) {
  __shared__ __align__(16) char smem[3][16384];

  const int t = threadIdx.x;
  const int lane = t & 63, w = t >> 6;
  const int lrow = lane & 15, lgrp = lane >> 4;
  const int bm = blockIdx.y * 128, bn = blockIdx.x * 128;
  const int wm = (w >> 1) * 64, wn = (w & 1) * 64;
  const int NT = K / 32;

  const f32x4 zero4 = {0.f, 0.f, 0.f, 0.f};
  f32x4 acc[4][4];
#pragma unroll
  for (int mi = 0; mi < 4; ++mi)
#pragma unroll
    for (int ni = 0; ni < 4; ++ni) acc[mi][ni] = zero4;

  auto stage_mat = [&](const uint16_t* __restrict__ G, int grow0,
                       char* ldsbase, int kt) {
#pragma unroll
    for (int j = 0; j < 2; ++j) {
      const int s = t + j * 256;
      const int row = s >> 2;
      const int sc = (s & 3) ^ ((row >> 1) & 3);
      load_lds16(G + (size_t)(grow0 + row) * K + kt + sc * 8,
                 ldsbase + j * 4096 + w * 1024);
    }
  };
  auto ldf = [&](const char* Mb, int base, int i) -> bf16x8 {
    const int row = base + i * 16 + lrow;
    return *(const bf16x8*)(Mb + row * 64 + ((lgrp ^ ((row >> 1) & 3)) << 4));
  };

  stage_mat(A, bm, smem[0], 0);
  stage_mat(B, bn, smem[0] + 8192, 0);
  stage_mat(A, bm, smem[1], 32);
  stage_mat(B, bn, smem[1] + 8192, 32);

  for (int kt = 0; kt < NT; ++kt) {
    char* cur = smem[kt % 3];
    if (kt < NT - 1) asm volatile("s_waitcnt vmcnt(4)" ::: "memory");
    else             asm volatile("s_waitcnt vmcnt(0)" ::: "memory");
    __builtin_amdgcn_s_barrier();

    if (kt + 2 < NT) {
      char* nx2 = smem[(kt + 2) % 3];
      stage_mat(A, bm, nx2, (kt + 2) * 32);
      stage_mat(B, bn, nx2 + 8192, (kt + 2) * 32);
    }

    bf16x8 aF[4], bF[4];
#pragma unroll
    for (int mi = 0; mi < 4; ++mi) aF[mi] = ldf(cur, wm, mi);
#pragma unroll
    for (int ni = 0; ni < 4; ++ni) bF[ni] = ldf(cur + 8192, wn, ni);
#pragma unroll
    for (int mi = 0; mi < 4; ++mi)
#pragma unroll
      for (int ni = 0; ni < 4; ++ni)
        acc[mi][ni] = __builtin_amdgcn_mfma_f32_16x16x32_bf16(
            aF[mi], bF[ni], acc[mi][ni], 0, 0, 0);
  }

#pragma unroll
  for (int mi = 0; mi < 4; ++mi) {
#pragma unroll
    for (int ni = 0; ni < 4; ++ni) {
      const int n = bn + wn + ni * 16 + lrow;
#pragma unroll
      for (int r = 0; r < 4; ++r) {
        const int m = bm + wm + mi * 16 + lgrp * 4 + r;
        const float v = acc[mi][ni][r] * scale;
        if (MODE == 2) {
          ((float*)C)[(size_t)m * N + n] = v;
        } else {
          const int h = m >> 6, d = m & 63;
          const int b = n >> 11, s = n & 2047;
          ((uint16_t*)C)[(((size_t)(b * NHEAD + h) * HDIM + d) * S_LEN) + s] =
              f2bf(v);
        }
      }
    }
  }
}

// ---------------- causal flash attention v5 (r13 exact — measured best) ---
// KVBLK=128 staged as two independent 64x64 K/V subtiles; barriers halve
// vs v4; both subtiles' QK MFMAs issue before sub0's softmax (cross-chain
// ILP). Pairs (p,15-p): uniform 17 tiles/block. Denominator on MFMA (oS).
__global__ __launch_bounds__(256, 2) void attn_kernel(
    const uint16_t* __restrict__ Q, const uint16_t* __restrict__ K,
    const uint16_t* __restrict__ Vt, uint16_t* __restrict__ O) {
  extern __shared__ __align__(16) char asmem[];  // 65536
  const int t = threadIdx.x, lane = t & 63, w = t >> 6;
  const int qcol = lane & 31, hi = lane >> 5;
  const int id = blockIdx.x;
  const int bh = (id & 7) * 8 + ((id >> 3) & 7);  // 8 heads per XCD
  const int p = id >> 6;                           // 0..7
  const int b = bh >> 5, h = bh & 31;

  const uint16_t* Qbh = Q + (size_t)bh * S_LEN * HDIM;
  const uint16_t* Kbh = K + (size_t)bh * S_LEN * HDIM;
  const uint16_t* Vbh = Vt + (size_t)bh * HDIM * S_LEN;

  const int srow = lane >> 3;
  const int schunk = (lane & 7) ^ srow;

  const short one_bf = (short)0x3F80;  // bf16 1.0
  const bf16x8 onesf = {one_bf, one_bf, one_bf, one_bf,
                        one_bf, one_bf, one_bf, one_bf};

  auto Kbuf = [&](int bi, int sub) -> char* {
    return asmem + (bi * 2 + sub) * 8192;
  };
  auto Vbuf = [&](int bi, int sub) -> char* {
    return asmem + 32768 + (bi * 2 + sub) * 8192;
  };

  auto stage = [&](int k0, int bi) {
#pragma unroll
    for (int sub = 0; sub < 2; ++sub) {
      const int kb = k0 + sub * 64;
#pragma unroll
      for (int j = 0; j < 2; ++j) {
        const int r = j * 32 + w * 8 + srow;
        load_lds16(Kbh + (size_t)(kb + r) * HDIM + schunk * 8,
                   Kbuf(bi, sub) + j * 4096 + w * 1024);
        load_lds16(Vbh + (size_t)r * S_LEN + kb + schunk * 8,
                   Vbuf(bi, sub) + j * 4096 + w * 1024);
      }
    }
  };

  const int rk0 = qcol, rk1 = 32 + qcol;
  const int x0 = qcol & 7;

  for (int pass = 0; pass < 2; ++pass) {
    const int jq = pass ? (15 - p) : p;        // 128-row q-tile index
    const int qw = jq * 128 + w * 32;
    const int qg = qw + qcol;

    bf16x8 qB[4];
    {
      const uint16_t* qp = Qbh + (size_t)qg * HDIM + hi * 8;
#pragma unroll
      for (int j = 0; j < 4; ++j) qB[j] = *(const bf16x8*)(qp + 16 * j);
    }

    f32x16 oacc0, oacc1, oS;
#pragma unroll
    for (int r = 0; r < 16; ++r) { oacc0[r] = 0.f; oacc1[r] = 0.f; oS[r] = 0.f; }

    auto qk = [&](const char* Kc, f32x16& s0, f32x16& s1) {
#pragma unroll
      for (int r = 0; r < 16; ++r) { s0[r] = 0.f; s1[r] = 0.f; }
      __builtin_amdgcn_s_setprio(1);
#pragma unroll
      for (int j = 0; j < 4; ++j) {
        bf16x8 kf0 = *(const bf16x8*)(Kc + rk0 * 128 + (((2*j+hi) ^ x0) << 4));
        bf16x8 kf1 = *(const bf16x8*)(Kc + rk1 * 128 + (((2*j+hi) ^ x0) << 4));
        s0 = mfma32(kf0, qB[j], s0);
        s1 = mfma32(kf1, qB[j], s1);
      }
      __builtin_amdgcn_s_setprio(0);
    };
    auto smx = [&](int k0s, f32x16& s0, f32x16& s1) {
      if (k0s + 63 > qw) {
#pragma unroll
        for (int r = 0; r < 16; ++r) {
          const int krow = (r & 3) + 8 * (r >> 2) + 4 * hi;
          s0[r] = (k0s + krow <= qg) ? exp2_hw(s0[r]) : 0.f;
          s1[r] = (k0s + 32 + krow <= qg) ? exp2_hw(s1[r]) : 0.f;
        }
      } else {
#pragma unroll
        for (int r = 0; r < 16; ++r) {
          s0[r] = exp2_hw(s0[r]);
          s1[r] = exp2_hw(s1[r]);
        }
      }
    };
    auto repack = [&](const f32x16& s0, const f32x16& s1, bf16x8 (&paf)[4]) {
#pragma unroll
      for (int tt = 0; tt < 4; ++tt) {
        const int o = 8 * (tt & 1);
        uint32_t a0, a1, a2, a3;
        if (tt < 2) {
          a0 = cvtpk(s0[o + 0], s0[o + 1]);
          a1 = cvtpk(s0[o + 2], s0[o + 3]);
          a2 = cvtpk(s0[o + 4], s0[o + 5]);
          a3 = cvtpk(s0[o + 6], s0[o + 7]);
        } else {
          a0 = cvtpk(s1[o + 0], s1[o + 1]);
          a1 = cvtpk(s1[o + 2], s1[o + 3]);
          a2 = cvtpk(s1[o + 4], s1[o + 5]);
          a3 = cvtpk(s1[o + 6], s1[o + 7]);
        }
        plswap(a0, a2);
        plswap(a1, a3);
        union { uint32_t u[4]; bf16x8 v; } pk;
        pk.u[0] = a0; pk.u[1] = a1; pk.u[2] = a2; pk.u[3] = a3;
        paf[tt] = pk.v;
      }
    };
    auto pv = [&](const char* Vc, const bf16x8 (&paf)[4]) {
      __builtin_amdgcn_s_setprio(1);
#pragma unroll
      for (int tt = 0; tt < 4; ++tt) {
        const int c = 2 * tt + hi;
        bf16x8 v0f = *(const bf16x8*)(Vc + rk0 * 128 + ((c ^ x0) << 4));
        bf16x8 v1f = *(const bf16x8*)(Vc + rk1 * 128 + ((c ^ x0) << 4));
        oacc0 = mfma32(paf[tt], v0f, oacc0);
        oacc1 = mfma32(paf[tt], v1f, oacc1);
        oS = mfma32(paf[tt], onesf, oS);
      }
      __builtin_amdgcn_s_setprio(0);
    };

    const int nt = jq + 1;   // 128-wide kv tiles
    for (int kt = 0; kt < nt; ++kt) {
      const int cur = kt & 1;
      const int k0 = kt * 128;
      if (kt == 0) { __syncthreads(); stage(0, 0); }
      __syncthreads();                      // stage(kt) landed
      if (kt + 1 < nt) stage((kt + 1) * 128, cur ^ 1);

      const bool a1 = (k0 + 64 <= qw + 31);  // sub1 active for this wave
      f32x16 s0a, s1a, s0b, s1b;
      qk(Kbuf(cur, 0), s0a, s1a);
      if (a1) qk(Kbuf(cur, 1), s0b, s1b);    // independent of sub0 softmax
      smx(k0, s0a, s1a);
      bf16x8 paf[4];
      repack(s0a, s1a, paf);
      pv(Vbuf(cur, 0), paf);
      if (a1) {
        smx(k0 + 64, s0b, s1b);
        repack(s0b, s1b, paf);
        pv(Vbuf(cur, 1), paf);
      }
    }

#pragma unroll
    for (int r = 0; r < 16; ++r) {
      const int qrow = (r & 3) + 8 * (r >> 2) + 4 * hi;
      const float inv = 1.0f / oS[r];
      const size_t base = ((size_t)b * S_LEN + qw + qrow) * 2048 + h * 64;
      O[base + qcol] = f2bf(oacc0[r] * inv);
      O[base + 32 + qcol] = f2bf(oacc1[r] * inv);
    }
  }
}

// ---------------- launcher ----------------
extern "C" void kernel_launch(void* const* d_in, const int* in_sizes, int n_in,
                              void* d_out, int out_size, void* d_ws,
                              size_t ws_size, hipStream_t stream) {
  const float* X  = (const float*)d_in[0];
  const float* Wq = (const float*)d_in[2];
  const float* Wk = (const float*)d_in[3];
  const float* Wv = (const float*)d_in[4];
  const float* Wo = (const float*)d_in[5];
  float* out = (float*)d_out;

  char* ws = (char*)d_ws;
  uint16_t* Xbf = (uint16_t*)ws;                    // 16.78 MB [4096][2048]
  uint16_t* Wqk = (uint16_t*)(ws + 16777216);       // 16.78 MB [4096][2048]
  uint16_t* Qb  = (uint16_t*)(ws + 33554432);       // 16.78 MB [B,NH,S,HD]
  uint16_t* Kb  = (uint16_t*)(ws + 50331648);       // 16.78 MB [B,NH,S,HD]
  uint16_t* Wsm = (uint16_t*)(ws + 67108864);       //  8.39 MB (Wv bf16)
  uint16_t* Wob = (uint16_t*)(ws + 75497472);       //  8.39 MB (Wo bf16)
  uint16_t* Vtb = Wqk;   // Vt aliases Wqk (dead after QK GEMM)
  uint16_t* Ob  = Xbf;   // O aliases Xbf (dead after Vt GEMM)

  // 1/sqrt(HD) * log2(e): softmax weights computed as 2^s (v_exp_f32 direct)
  const float qscale = 0.125f * 1.4426950408889634f;

  hipFuncSetAttribute((const void*)gemm_qk,
                      hipFuncAttributeMaxDynamicSharedMemorySize, 98304);
  hipFuncSetAttribute((const void*)attn_kernel,
                      hipFuncAttributeMaxDynamicSharedMemorySize, 65536);

  conv_batch<<<24576, 256, 0, stream>>>(X, Wq, Wk, Wv, Wo, Xbf, Wqk, Wsm, Wob);
  gemm_qk<<<256, 512, 98304, stream>>>(Xbf, Wqk, Qb, Kb, qscale);
  gemm_nt<1><<<dim3(32, 16), 256, 0, stream>>>(Wsm, Xbf, Vtb, 2048, 4096, 2048, 1.0f);
  attn_kernel<<<512, 256, 65536, stream>>>(Qb, Kb, Vtb, Ob);
  gemm_nt<2><<<dim3(16, 32), 256, 0, stream>>>(Ob, Wob, out, 4096, 2048, 2048, 1.0f);
}

// Round 16
// 215.506 us; speedup vs baseline: 1.0333x; 1.0300x over previous
//
#include <hip/hip_runtime.h>
#include <hip/hip_bf16.h>
#include <stdint.h>

// Problem constants: B=2, S=2048, H=2048, NH=32, HD=64
#define S_LEN 2048
#define NHEAD 32
#define HDIM  64

using bf16x8 = __attribute__((ext_vector_type(8))) short;
using f32x4  = __attribute__((ext_vector_type(4))) float;
using f32x16 = __attribute__((ext_vector_type(16))) float;

__device__ __forceinline__ uint16_t f2bf(float f) {
  union { float f; uint32_t u; } c; c.f = f;
  uint32_t u = c.u;
  return (uint16_t)((u + 0x7FFFu + ((u >> 16) & 1u)) >> 16);
}

__device__ __forceinline__ void load_lds16(const void* g, void* l) {
  __builtin_amdgcn_global_load_lds(
      (const __attribute__((address_space(1))) void*)g,
      (__attribute__((address_space(3))) void*)l, 16, 0, 0);
}

__device__ __forceinline__ f32x16 mfma32(bf16x8 a, bf16x8 b, f32x16 c) {
  return __builtin_amdgcn_mfma_f32_32x32x16_bf16(a, b, c, 0, 0, 0);
}

__device__ __forceinline__ uint32_t cvtpk(float lo, float hi_) {
  uint32_t d;
  asm("v_cvt_pk_bf16_f32 %0, %1, %2" : "=v"(d) : "v"(lo), "v"(hi_));
  return d;
}
__device__ __forceinline__ void plswap(uint32_t& a, uint32_t& b) {
  asm volatile("v_permlane32_swap_b32 %0, %1" : "+v"(a), "+v"(b));
}
// 2^x directly (Q pre-scaled by log2e so 2^s == e^{s_true})
__device__ __forceinline__ float exp2_hw(float x) {
  float r;
  asm("v_exp_f32 %0, %1" : "=v"(r) : "v"(x));
  return r;
}

// ---------------- batched fp32 -> bf16 conversion (X + all 4 weights) -----
__global__ __launch_bounds__(256) void conv_batch(
    const float* __restrict__ X, const float* __restrict__ Wq,
    const float* __restrict__ Wk, const float* __restrict__ Wv,
    const float* __restrict__ Wo, uint16_t* __restrict__ Xbf,
    uint16_t* __restrict__ Wqk, uint16_t* __restrict__ Wvb,
    uint16_t* __restrict__ Wob) {
  int i = blockIdx.x * 256 + threadIdx.x;  // total 6291456
  const float* src; uint16_t* dst; int o;
  if (i < 2097152)      { src = X;  dst = Xbf;           o = i; }
  else if (i < 3145728) { src = Wq; dst = Wqk;           o = i - 2097152; }
  else if (i < 4194304) { src = Wk; dst = Wqk + 4194304; o = i - 3145728; }
  else if (i < 5242880) { src = Wv; dst = Wvb;           o = i - 4194304; }
  else                  { src = Wo; dst = Wob;           o = i - 5242880; }
  float4 v = ((const float4*)src)[o];
  uint64_t packed = (uint64_t)f2bf(v.x) | ((uint64_t)f2bf(v.y) << 16) |
                    ((uint64_t)f2bf(v.z) << 32) | ((uint64_t)f2bf(v.w) << 48);
  ((uint64_t*)dst)[o] = packed;
}

// ---------------- fused QK GEMM v7: 256x256, BK=64, 1 barrier/tile --------
// Each wave's A frags live in A-half(wr), B frags in B-half(wc>>1) -> a
// single vmcnt(0)+barrier per BK=64 tile both publishes tile t's staging
// and retires tile t-1's reads; phases 2-4 need NO barrier (stages target
// the other buffer). 4 phases: {ds_read quadrant || stage half(t+1) ||
// 16 MFMA}; quadrant order (m0n0),(m0n1),(m1n1),(m1n0) keeps b0 live.
// 2 x 64KB LDS, 1 block/CU. Barrier density 1/4 of r6.
__global__ __launch_bounds__(512, 2) void gemm_qk(
    const uint16_t* __restrict__ A, const uint16_t* __restrict__ Bw,
    uint16_t* __restrict__ Qo, uint16_t* __restrict__ Ko, float qscale) {
  extern __shared__ char smem[];  // 2 * 65536
  const int t = threadIdx.x;
  const int lane = t & 63, w = t >> 6;
  const int lrow = lane & 15, lgrp = lane >> 4;
  const int wr = w >> 2, wc = w & 3;
  const int id = blockIdx.x;
  const int swz = (id & 7) * 32 + (id >> 3);        // bijective XCD swizzle
  const int bm = (swz & 15) * 256, bn = (swz >> 4) * 256;
  constexpr int NT = 2048 / 64;  // 32

  const f32x4 zero4 = {0.f, 0.f, 0.f, 0.f};
  f32x4 acc[8][4];
#pragma unroll
  for (int mi = 0; mi < 8; ++mi)
#pragma unroll
    for (int ni = 0; ni < 4; ++ni) acc[mi][ni] = zero4;

  // stage one 128-row x 64-col half-tile (16KB, 2 loads/thread).
  // slot s: lr=s>>3, chunk=s&7; source chunk pre-swizzled c^(lr&7);
  // LDS dest linear (wave-uniform base + lane*16).
  auto stage_half = [&](const uint16_t* __restrict__ G, int grow0,
                        char* dstHalf, int kt) {
#pragma unroll
    for (int j = 0; j < 2; ++j) {
      const int s = t + j * 512;
      const int lr = s >> 3;
      const int sc = (s & 7) ^ (lr & 7);
      load_lds16(G + (size_t)(grow0 + lr) * 2048 + kt * 64 + sc * 8,
                 dstHalf + j * 8192 + w * 1024);
    }
  };
  // A frag: quadrant mh (0/1), mi2 0..3, kk 0..1 -> half wr
  auto ldA = [&](const char* bufA, int mh, int mi2, int kk) -> bf16x8 {
    const int lr = mh * 64 + mi2 * 16 + lrow;
    const int c = kk * 4 + lgrp;
    return *(const bf16x8*)(bufA + wr * 16384 + lr * 128 +
                            ((c ^ (lr & 7)) << 4));
  };
  // B frag: quadrant nh (0/1), ni2 0..1, kk 0..1 -> half wc>>1
  auto ldB = [&](const char* bufB, int nh, int ni2, int kk) -> bf16x8 {
    const int lr = (wc & 1) * 64 + nh * 32 + ni2 * 16 + lrow;
    const int c = kk * 4 + lgrp;
    return *(const bf16x8*)(bufB + (wc >> 1) * 16384 + lr * 128 +
                            ((c ^ (lr & 7)) << 4));
  };

  // prologue: stage all 4 halves of tile 0 into buf 0 (8 loads/thread)
  stage_half(A, bm, smem, 0);
  stage_half(A, bm + 128, smem + 16384, 0);
  stage_half(Bw, bn, smem + 32768, 0);
  stage_half(Bw, bn + 128, smem + 49152, 0);

  for (int kt = 0; kt < NT; ++kt) {
    char* bufc = smem + (kt & 1) * 65536;
    char* bufn = smem + ((kt + 1) & 1) * 65536;
    const char* Ac = bufc;
    const char* Bc = bufc + 32768;
    const bool pre = (kt + 1 < NT);

    // ---- tile-top sync: own stages of tile t drained; barrier publishes
    // all waves' stages AND retires all waves' reads of tile t-1.
    asm volatile("s_waitcnt vmcnt(0)" ::: "memory");
    __builtin_amdgcn_s_barrier();

    bf16x8 aF[4][2], b0[2][2], b1[2][2];

    // ---- p1: quad (m0,n0); read A-m0 (8) + B-n0 (4); stage A0(t+1)
#pragma unroll
    for (int mi2 = 0; mi2 < 4; ++mi2)
#pragma unroll
      for (int kk = 0; kk < 2; ++kk) aF[mi2][kk] = ldA(Ac, 0, mi2, kk);
#pragma unroll
    for (int ni2 = 0; ni2 < 2; ++ni2)
#pragma unroll
      for (int kk = 0; kk < 2; ++kk) b0[ni2][kk] = ldB(Bc, 0, ni2, kk);
    if (pre) stage_half(A, bm, bufn, kt + 1);
    asm volatile("s_waitcnt lgkmcnt(0)" ::: "memory");
    __builtin_amdgcn_sched_barrier(0);
    __builtin_amdgcn_s_setprio(1);
#pragma unroll
    for (int mi2 = 0; mi2 < 4; ++mi2)
#pragma unroll
      for (int ni2 = 0; ni2 < 2; ++ni2)
#pragma unroll
        for (int kk = 0; kk < 2; ++kk)
          acc[mi2][ni2] = __builtin_amdgcn_mfma_f32_16x16x32_bf16(
              aF[mi2][kk], b0[ni2][kk], acc[mi2][ni2], 0, 0, 0);
    __builtin_amdgcn_s_setprio(0);

    // ---- p2: quad (m0,n1); read B-n1 (4); stage A1(t+1)
#pragma unroll
    for (int ni2 = 0; ni2 < 2; ++ni2)
#pragma unroll
      for (int kk = 0; kk < 2; ++kk) b1[ni2][kk] = ldB(Bc, 1, ni2, kk);
    if (pre) stage_half(A, bm + 128, bufn + 16384, kt + 1);
    asm volatile("s_waitcnt lgkmcnt(0)" ::: "memory");
    __builtin_amdgcn_sched_barrier(0);
    __builtin_amdgcn_s_setprio(1);
#pragma unroll
    for (int mi2 = 0; mi2 < 4; ++mi2)
#pragma unroll
      for (int ni2 = 0; ni2 < 2; ++ni2)
#pragma unroll
        for (int kk = 0; kk < 2; ++kk)
          acc[mi2][2 + ni2] = __builtin_amdgcn_mfma_f32_16x16x32_bf16(
              aF[mi2][kk], b1[ni2][kk], acc[mi2][2 + ni2], 0, 0, 0);
    __builtin_amdgcn_s_setprio(0);

    // ---- p3: quad (m1,n1); read A-m1 (8); stage B0(t+1)
#pragma unroll
    for (int mi2 = 0; mi2 < 4; ++mi2)
#pragma unroll
      for (int kk = 0; kk < 2; ++kk) aF[mi2][kk] = ldA(Ac, 1, mi2, kk);
    if (pre) stage_half(Bw, bn, bufn + 32768, kt + 1);
    asm volatile("s_waitcnt lgkmcnt(0)" ::: "memory");
    __builtin_amdgcn_sched_barrier(0);
    __builtin_amdgcn_s_setprio(1);
#pragma unroll
    for (int mi2 = 0; mi2 < 4; ++mi2)
#pragma unroll
      for (int ni2 = 0; ni2 < 2; ++ni2)
#pragma unroll
        for (int kk = 0; kk < 2; ++kk)
          acc[4 + mi2][2 + ni2] = __builtin_amdgcn_mfma_f32_16x16x32_bf16(
              aF[mi2][kk], b1[ni2][kk], acc[4 + mi2][2 + ni2], 0, 0, 0);
    __builtin_amdgcn_s_setprio(0);

    // ---- p4: quad (m1,n0); no reads (b0 live); stage B1(t+1)
    if (pre) stage_half(Bw, bn + 128, bufn + 49152, kt + 1);
    __builtin_amdgcn_s_setprio(1);
#pragma unroll
    for (int mi2 = 0; mi2 < 4; ++mi2)
#pragma unroll
      for (int ni2 = 0; ni2 < 2; ++ni2)
#pragma unroll
        for (int kk = 0; kk < 2; ++kk)
          acc[4 + mi2][ni2] = __builtin_amdgcn_mfma_f32_16x16x32_bf16(
              aF[mi2][kk], b0[ni2][kk], acc[4 + mi2][ni2], 0, 0, 0);
    __builtin_amdgcn_s_setprio(0);
  }

  // epilogue: row = lgrp*4+r, col = lrow (m89 layout)
  const bool isQ = (bn < 2048);
#pragma unroll
  for (int mi = 0; mi < 8; ++mi) {
#pragma unroll
    for (int ni = 0; ni < 4; ++ni) {
      const int n = bn + wc * 64 + ni * 16 + lrow;
      const int n2 = isQ ? n : (n - 2048);
      const int h = n2 >> 6, d = n2 & 63;
#pragma unroll
      for (int r = 0; r < 4; ++r) {
        const int m = bm + wr * 128 + mi * 16 + lgrp * 4 + r;
        const int b = m >> 11, s = m & 2047;
        const size_t off = (((size_t)(b * NHEAD + h) * S_LEN + s) * HDIM) + d;
        if (isQ) Qo[off] = f2bf(acc[mi][ni][r] * qscale);
        else     Ko[off] = f2bf(acc[mi][ni][r]);
      }
    }
  }
}

// ---------------- NT GEMM 128^2, BK=32, 3-buf, 1 barrier/tile (r6) --------
template<int MODE>
__global__ __launch_bounds__(256, 3) void gemm_nt(
    const uint16_t* __restrict__ A, const uint16_t* __restrict__ B,
    void* __restrict__ C, int M, int N, int K, float scale) {
  __shared__ __align__(16) char smem[3][16384];

  const int t = threadIdx.x;
  const int lane = t & 63, w = t >> 6;
  const int lrow = lane & 15, lgrp = lane >> 4;
  const int bm = blockIdx.y * 128, bn = blockIdx.x * 128;
  const int wm = (w >> 1) * 64, wn = (w & 1) * 64;
  const int NT = K / 32;

  const f32x4 zero4 = {0.f, 0.f, 0.f, 0.f};
  f32x4 acc[4][4];
#pragma unroll
  for (int mi = 0; mi < 4; ++mi)
#pragma unroll
    for (int ni = 0; ni < 4; ++ni) acc[mi][ni] = zero4;

  auto stage_mat = [&](const uint16_t* __restrict__ G, int grow0,
                       char* ldsbase, int kt) {
#pragma unroll
    for (int j = 0; j < 2; ++j) {
      const int s = t + j * 256;
      const int row = s >> 2;
      const int sc = (s & 3) ^ ((row >> 1) & 3);
      load_lds16(G + (size_t)(grow0 + row) * K + kt + sc * 8,
                 ldsbase + j * 4096 + w * 1024);
    }
  };
  auto ldf = [&](const char* Mb, int base, int i) -> bf16x8 {
    const int row = base + i * 16 + lrow;
    return *(const bf16x8*)(Mb + row * 64 + ((lgrp ^ ((row >> 1) & 3)) << 4));
  };

  stage_mat(A, bm, smem[0], 0);
  stage_mat(B, bn, smem[0] + 8192, 0);
  stage_mat(A, bm, smem[1], 32);
  stage_mat(B, bn, smem[1] + 8192, 32);

  for (int kt = 0; kt < NT; ++kt) {
    char* cur = smem[kt % 3];
    if (kt < NT - 1) asm volatile("s_waitcnt vmcnt(4)" ::: "memory");
    else             asm volatile("s_waitcnt vmcnt(0)" ::: "memory");
    __builtin_amdgcn_s_barrier();

    if (kt + 2 < NT) {
      char* nx2 = smem[(kt + 2) % 3];
      stage_mat(A, bm, nx2, (kt + 2) * 32);
      stage_mat(B, bn, nx2 + 8192, (kt + 2) * 32);
    }

    bf16x8 aF[4], bF[4];
#pragma unroll
    for (int mi = 0; mi < 4; ++mi) aF[mi] = ldf(cur, wm, mi);
#pragma unroll
    for (int ni = 0; ni < 4; ++ni) bF[ni] = ldf(cur + 8192, wn, ni);
#pragma unroll
    for (int mi = 0; mi < 4; ++mi)
#pragma unroll
      for (int ni = 0; ni < 4; ++ni)
        acc[mi][ni] = __builtin_amdgcn_mfma_f32_16x16x32_bf16(
            aF[mi], bF[ni], acc[mi][ni], 0, 0, 0);
  }

#pragma unroll
  for (int mi = 0; mi < 4; ++mi) {
#pragma unroll
    for (int ni = 0; ni < 4; ++ni) {
      const int n = bn + wn + ni * 16 + lrow;
#pragma unroll
      for (int r = 0; r < 4; ++r) {
        const int m = bm + wm + mi * 16 + lgrp * 4 + r;
        const float v = acc[mi][ni][r] * scale;
        if (MODE == 2) {
          ((float*)C)[(size_t)m * N + n] = v;
        } else {
          const int h = m >> 6, d = m & 63;
          const int b = n >> 11, s = n & 2047;
          ((uint16_t*)C)[(((size_t)(b * NHEAD + h) * HDIM + d) * S_LEN) + s] =
              f2bf(v);
        }
      }
    }
  }
}

// ---------------- causal flash attention v5 (r13 exact — measured best) ---
__global__ __launch_bounds__(256, 2) void attn_kernel(
    const uint16_t* __restrict__ Q, const uint16_t* __restrict__ K,
    const uint16_t* __restrict__ Vt, uint16_t* __restrict__ O) {
  extern __shared__ __align__(16) char asmem[];  // 65536
  const int t = threadIdx.x, lane = t & 63, w = t >> 6;
  const int qcol = lane & 31, hi = lane >> 5;
  const int id = blockIdx.x;
  const int bh = (id & 7) * 8 + ((id >> 3) & 7);  // 8 heads per XCD
  const int p = id >> 6;                           // 0..7
  const int b = bh >> 5, h = bh & 31;

  const uint16_t* Qbh = Q + (size_t)bh * S_LEN * HDIM;
  const uint16_t* Kbh = K + (size_t)bh * S_LEN * HDIM;
  const uint16_t* Vbh = Vt + (size_t)bh * HDIM * S_LEN;

  const int srow = lane >> 3;
  const int schunk = (lane & 7) ^ srow;

  const short one_bf = (short)0x3F80;  // bf16 1.0
  const bf16x8 onesf = {one_bf, one_bf, one_bf, one_bf,
                        one_bf, one_bf, one_bf, one_bf};

  auto Kbuf = [&](int bi, int sub) -> char* {
    return asmem + (bi * 2 + sub) * 8192;
  };
  auto Vbuf = [&](int bi, int sub) -> char* {
    return asmem + 32768 + (bi * 2 + sub) * 8192;
  };

  auto stage = [&](int k0, int bi) {
#pragma unroll
    for (int sub = 0; sub < 2; ++sub) {
      const int kb = k0 + sub * 64;
#pragma unroll
      for (int j = 0; j < 2; ++j) {
        const int r = j * 32 + w * 8 + srow;
        load_lds16(Kbh + (size_t)(kb + r) * HDIM + schunk * 8,
                   Kbuf(bi, sub) + j * 4096 + w * 1024);
        load_lds16(Vbh + (size_t)r * S_LEN + kb + schunk * 8,
                   Vbuf(bi, sub) + j * 4096 + w * 1024);
      }
    }
  };

  const int rk0 = qcol, rk1 = 32 + qcol;
  const int x0 = qcol & 7;

  for (int pass = 0; pass < 2; ++pass) {
    const int jq = pass ? (15 - p) : p;        // 128-row q-tile index
    const int qw = jq * 128 + w * 32;
    const int qg = qw + qcol;

    bf16x8 qB[4];
    {
      const uint16_t* qp = Qbh + (size_t)qg * HDIM + hi * 8;
#pragma unroll
      for (int j = 0; j < 4; ++j) qB[j] = *(const bf16x8*)(qp + 16 * j);
    }

    f32x16 oacc0, oacc1, oS;
#pragma unroll
    for (int r = 0; r < 16; ++r) { oacc0[r] = 0.f; oacc1[r] = 0.f; oS[r] = 0.f; }

    auto qk = [&](const char* Kc, f32x16& s0, f32x16& s1) {
#pragma unroll
      for (int r = 0; r < 16; ++r) { s0[r] = 0.f; s1[r] = 0.f; }
      __builtin_amdgcn_s_setprio(1);
#pragma unroll
      for (int j = 0; j < 4; ++j) {
        bf16x8 kf0 = *(const bf16x8*)(Kc + rk0 * 128 + (((2*j+hi) ^ x0) << 4));
        bf16x8 kf1 = *(const bf16x8*)(Kc + rk1 * 128 + (((2*j+hi) ^ x0) << 4));
        s0 = mfma32(kf0, qB[j], s0);
        s1 = mfma32(kf1, qB[j], s1);
      }
      __builtin_amdgcn_s_setprio(0);
    };
    auto smx = [&](int k0s, f32x16& s0, f32x16& s1) {
      if (k0s + 63 > qw) {
#pragma unroll
        for (int r = 0; r < 16; ++r) {
          const int krow = (r & 3) + 8 * (r >> 2) + 4 * hi;
          s0[r] = (k0s + krow <= qg) ? exp2_hw(s0[r]) : 0.f;
          s1[r] = (k0s + 32 + krow <= qg) ? exp2_hw(s1[r]) : 0.f;
        }
      } else {
#pragma unroll
        for (int r = 0; r < 16; ++r) {
          s0[r] = exp2_hw(s0[r]);
          s1[r] = exp2_hw(s1[r]);
        }
      }
    };
    auto repack = [&](const f32x16& s0, const f32x16& s1, bf16x8 (&paf)[4]) {
#pragma unroll
      for (int tt = 0; tt < 4; ++tt) {
        const int o = 8 * (tt & 1);
        uint32_t a0, a1, a2, a3;
        if (tt < 2) {
          a0 = cvtpk(s0[o + 0], s0[o + 1]);
          a1 = cvtpk(s0[o + 2], s0[o + 3]);
          a2 = cvtpk(s0[o + 4], s0[o + 5]);
          a3 = cvtpk(s0[o + 6], s0[o + 7]);
        } else {
          a0 = cvtpk(s1[o + 0], s1[o + 1]);
          a1 = cvtpk(s1[o + 2], s1[o + 3]);
          a2 = cvtpk(s1[o + 4], s1[o + 5]);
          a3 = cvtpk(s1[o + 6], s1[o + 7]);
        }
        plswap(a0, a2);
        plswap(a1, a3);
        union { uint32_t u[4]; bf16x8 v; } pk;
        pk.u[0] = a0; pk.u[1] = a1; pk.u[2] = a2; pk.u[3] = a3;
        paf[tt] = pk.v;
      }
    };
    auto pv = [&](const char* Vc, const bf16x8 (&paf)[4]) {
      __builtin_amdgcn_s_setprio(1);
#pragma unroll
      for (int tt = 0; tt < 4; ++tt) {
        const int c = 2 * tt + hi;
        bf16x8 v0f = *(const bf16x8*)(Vc + rk0 * 128 + ((c ^ x0) << 4));
        bf16x8 v1f = *(const bf16x8*)(Vc + rk1 * 128 + ((c ^ x0) << 4));
        oacc0 = mfma32(paf[tt], v0f, oacc0);
        oacc1 = mfma32(paf[tt], v1f, oacc1);
        oS = mfma32(paf[tt], onesf, oS);
      }
      __builtin_amdgcn_s_setprio(0);
    };

    const int nt = jq + 1;   // 128-wide kv tiles
    for (int kt = 0; kt < nt; ++kt) {
      const int cur = kt & 1;
      const int k0 = kt * 128;
      if (kt == 0) { __syncthreads(); stage(0, 0); }
      __syncthreads();                      // stage(kt) landed
      if (kt + 1 < nt) stage((kt + 1) * 128, cur ^ 1);

      const bool a1 = (k0 + 64 <= qw + 31);  // sub1 active for this wave
      f32x16 s0a, s1a, s0b, s1b;
      qk(Kbuf(cur, 0), s0a, s1a);
      if (a1) qk(Kbuf(cur, 1), s0b, s1b);    // independent of sub0 softmax
      smx(k0, s0a, s1a);
      bf16x8 paf[4];
      repack(s0a, s1a, paf);
      pv(Vbuf(cur, 0), paf);
      if (a1) {
        smx(k0 + 64, s0b, s1b);
        repack(s0b, s1b, paf);
        pv(Vbuf(cur, 1), paf);
      }
    }

#pragma unroll
    for (int r = 0; r < 16; ++r) {
      const int qrow = (r & 3) + 8 * (r >> 2) + 4 * hi;
      const float inv = 1.0f / oS[r];
      const size_t base = ((size_t)b * S_LEN + qw + qrow) * 2048 + h * 64;
      O[base + qcol] = f2bf(oacc0[r] * inv);
      O[base + 32 + qcol] = f2bf(oacc1[r] * inv);
    }
  }
}

// ---------------- launcher ----------------
extern "C" void kernel_launch(void* const* d_in, const int* in_sizes, int n_in,
                              void* d_out, int out_size, void* d_ws,
                              size_t ws_size, hipStream_t stream) {
  const float* X  = (const float*)d_in[0];
  const float* Wq = (const float*)d_in[2];
  const float* Wk = (const float*)d_in[3];
  const float* Wv = (const float*)d_in[4];
  const float* Wo = (const float*)d_in[5];
  float* out = (float*)d_out;

  char* ws = (char*)d_ws;
  uint16_t* Xbf = (uint16_t*)ws;                    // 16.78 MB [4096][2048]
  uint16_t* Wqk = (uint16_t*)(ws + 16777216);       // 16.78 MB [4096][2048]
  uint16_t* Qb  = (uint16_t*)(ws + 33554432);       // 16.78 MB [B,NH,S,HD]
  uint16_t* Kb  = (uint16_t*)(ws + 50331648);       // 16.78 MB [B,NH,S,HD]
  uint16_t* Wsm = (uint16_t*)(ws + 67108864);       //  8.39 MB (Wv bf16)
  uint16_t* Wob = (uint16_t*)(ws + 75497472);       //  8.39 MB (Wo bf16)
  uint16_t* Vtb = Wqk;   // Vt aliases Wqk (dead after QK GEMM)
  uint16_t* Ob  = Xbf;   // O aliases Xbf (dead after Vt GEMM)

  // 1/sqrt(HD) * log2(e): softmax weights computed as 2^s (v_exp_f32 direct)
  const float qscale = 0.125f * 1.4426950408889634f;

  hipFuncSetAttribute((const void*)gemm_qk,
                      hipFuncAttributeMaxDynamicSharedMemorySize, 131072);
  hipFuncSetAttribute((const void*)attn_kernel,
                      hipFuncAttributeMaxDynamicSharedMemorySize, 65536);

  conv_batch<<<24576, 256, 0, stream>>>(X, Wq, Wk, Wv, Wo, Xbf, Wqk, Wsm, Wob);
  gemm_qk<<<256, 512, 131072, stream>>>(Xbf, Wqk, Qb, Kb, qscale);
  gemm_nt<1><<<dim3(32, 16), 256, 0, stream>>>(Wsm, Xbf, Vtb, 2048, 4096, 2048, 1.0f);
  attn_kernel<<<512, 256, 65536, stream>>>(Qb, Kb, Vtb, Ob);
  gemm_nt<2><<<dim3(16, 32), 256, 0, stream>>>(Ob, Wob, out, 4096, 2048, 2048, 1.0f);
}

// Round 17
// 205.120 us; speedup vs baseline: 1.0856x; 1.0506x over previous
//
#include <hip/hip_runtime.h>
#include <hip/hip_bf16.h>
#include <stdint.h>

// Problem constants: B=2, S=2048, H=2048, NH=32, HD=64
#define S_LEN 2048
#define NHEAD 32
#define HDIM  64

using bf16x8 = __attribute__((ext_vector_type(8))) short;
using f32x4  = __attribute__((ext_vector_type(4))) float;
using f32x16 = __attribute__((ext_vector_type(16))) float;

__device__ __forceinline__ uint16_t f2bf(float f) {
  union { float f; uint32_t u; } c; c.f = f;
  uint32_t u = c.u;
  return (uint16_t)((u + 0x7FFFu + ((u >> 16) & 1u)) >> 16);
}

__device__ __forceinline__ void load_lds16(const void* g, void* l) {
  __builtin_amdgcn_global_load_lds(
      (const __attribute__((address_space(1))) void*)g,
      (__attribute__((address_space(3))) void*)l, 16, 0, 0);
}

__device__ __forceinline__ f32x16 mfma32(bf16x8 a, bf16x8 b, f32x16 c) {
  return __builtin_amdgcn_mfma_f32_32x32x16_bf16(a, b, c, 0, 0, 0);
}

__device__ __forceinline__ uint32_t cvtpk(float lo, float hi_) {
  uint32_t d;
  asm("v_cvt_pk_bf16_f32 %0, %1, %2" : "=v"(d) : "v"(lo), "v"(hi_));
  return d;
}
__device__ __forceinline__ void plswap(uint32_t& a, uint32_t& b) {
  asm volatile("v_permlane32_swap_b32 %0, %1" : "+v"(a), "+v"(b));
}
// 2^x directly (Q pre-scaled by log2e so 2^s == e^{s_true})
__device__ __forceinline__ float exp2_hw(float x) {
  float r;
  asm("v_exp_f32 %0, %1" : "=v"(r) : "v"(x));
  return r;
}

// ---------------- batched fp32 -> bf16 conversion (X + all 4 weights) -----
__global__ __launch_bounds__(256) void conv_batch(
    const float* __restrict__ X, const float* __restrict__ Wq,
    const float* __restrict__ Wk, const float* __restrict__ Wv,
    const float* __restrict__ Wo, uint16_t* __restrict__ Xbf,
    uint16_t* __restrict__ Wqk, uint16_t* __restrict__ Wvb,
    uint16_t* __restrict__ Wob) {
  int i = blockIdx.x * 256 + threadIdx.x;  // total 6291456
  const float* src; uint16_t* dst; int o;
  if (i < 2097152)      { src = X;  dst = Xbf;           o = i; }
  else if (i < 3145728) { src = Wq; dst = Wqk;           o = i - 2097152; }
  else if (i < 4194304) { src = Wk; dst = Wqk + 4194304; o = i - 3145728; }
  else if (i < 5242880) { src = Wv; dst = Wvb;           o = i - 4194304; }
  else                  { src = Wo; dst = Wob;           o = i - 5242880; }
  float4 v = ((const float4*)src)[o];
  uint64_t packed = (uint64_t)f2bf(v.x) | ((uint64_t)f2bf(v.y) << 16) |
                    ((uint64_t)f2bf(v.z) << 32) | ((uint64_t)f2bf(v.w) << 48);
  ((uint64_t*)dst)[o] = packed;
}

// ---------------- fused QK GEMM v7: 256x256, BK=64, 1 barrier/tile --------
// (r16 — measured 62.3 us / MfmaUtil 45.5%)
__global__ __launch_bounds__(512, 2) void gemm_qk(
    const uint16_t* __restrict__ A, const uint16_t* __restrict__ Bw,
    uint16_t* __restrict__ Qo, uint16_t* __restrict__ Ko, float qscale) {
  extern __shared__ char smem[];  // 2 * 65536
  const int t = threadIdx.x;
  const int lane = t & 63, w = t >> 6;
  const int lrow = lane & 15, lgrp = lane >> 4;
  const int wr = w >> 2, wc = w & 3;
  const int id = blockIdx.x;
  const int swz = (id & 7) * 32 + (id >> 3);        // bijective XCD swizzle
  const int bm = (swz & 15) * 256, bn = (swz >> 4) * 256;
  constexpr int NT = 2048 / 64;  // 32

  const f32x4 zero4 = {0.f, 0.f, 0.f, 0.f};
  f32x4 acc[8][4];
#pragma unroll
  for (int mi = 0; mi < 8; ++mi)
#pragma unroll
    for (int ni = 0; ni < 4; ++ni) acc[mi][ni] = zero4;

  auto stage_half = [&](const uint16_t* __restrict__ G, int grow0,
                        char* dstHalf, int kt) {
#pragma unroll
    for (int j = 0; j < 2; ++j) {
      const int s = t + j * 512;
      const int lr = s >> 3;
      const int sc = (s & 7) ^ (lr & 7);
      load_lds16(G + (size_t)(grow0 + lr) * 2048 + kt * 64 + sc * 8,
                 dstHalf + j * 8192 + w * 1024);
    }
  };
  auto ldA = [&](const char* bufA, int mh, int mi2, int kk) -> bf16x8 {
    const int lr = mh * 64 + mi2 * 16 + lrow;
    const int c = kk * 4 + lgrp;
    return *(const bf16x8*)(bufA + wr * 16384 + lr * 128 +
                            ((c ^ (lr & 7)) << 4));
  };
  auto ldB = [&](const char* bufB, int nh, int ni2, int kk) -> bf16x8 {
    const int lr = (wc & 1) * 64 + nh * 32 + ni2 * 16 + lrow;
    const int c = kk * 4 + lgrp;
    return *(const bf16x8*)(bufB + (wc >> 1) * 16384 + lr * 128 +
                            ((c ^ (lr & 7)) << 4));
  };

  stage_half(A, bm, smem, 0);
  stage_half(A, bm + 128, smem + 16384, 0);
  stage_half(Bw, bn, smem + 32768, 0);
  stage_half(Bw, bn + 128, smem + 49152, 0);

  for (int kt = 0; kt < NT; ++kt) {
    char* bufc = smem + (kt & 1) * 65536;
    char* bufn = smem + ((kt + 1) & 1) * 65536;
    const char* Ac = bufc;
    const char* Bc = bufc + 32768;
    const bool pre = (kt + 1 < NT);

    asm volatile("s_waitcnt vmcnt(0)" ::: "memory");
    __builtin_amdgcn_s_barrier();

    bf16x8 aF[4][2], b0[2][2], b1[2][2];

    // p1: quad (m0,n0); stage A0(t+1)
#pragma unroll
    for (int mi2 = 0; mi2 < 4; ++mi2)
#pragma unroll
      for (int kk = 0; kk < 2; ++kk) aF[mi2][kk] = ldA(Ac, 0, mi2, kk);
#pragma unroll
    for (int ni2 = 0; ni2 < 2; ++ni2)
#pragma unroll
      for (int kk = 0; kk < 2; ++kk) b0[ni2][kk] = ldB(Bc, 0, ni2, kk);
    if (pre) stage_half(A, bm, bufn, kt + 1);
    asm volatile("s_waitcnt lgkmcnt(0)" ::: "memory");
    __builtin_amdgcn_sched_barrier(0);
    __builtin_amdgcn_s_setprio(1);
#pragma unroll
    for (int mi2 = 0; mi2 < 4; ++mi2)
#pragma unroll
      for (int ni2 = 0; ni2 < 2; ++ni2)
#pragma unroll
        for (int kk = 0; kk < 2; ++kk)
          acc[mi2][ni2] = __builtin_amdgcn_mfma_f32_16x16x32_bf16(
              aF[mi2][kk], b0[ni2][kk], acc[mi2][ni2], 0, 0, 0);
    __builtin_amdgcn_s_setprio(0);

    // p2: quad (m0,n1); stage A1(t+1)
#pragma unroll
    for (int ni2 = 0; ni2 < 2; ++ni2)
#pragma unroll
      for (int kk = 0; kk < 2; ++kk) b1[ni2][kk] = ldB(Bc, 1, ni2, kk);
    if (pre) stage_half(A, bm + 128, bufn + 16384, kt + 1);
    asm volatile("s_waitcnt lgkmcnt(0)" ::: "memory");
    __builtin_amdgcn_sched_barrier(0);
    __builtin_amdgcn_s_setprio(1);
#pragma unroll
    for (int mi2 = 0; mi2 < 4; ++mi2)
#pragma unroll
      for (int ni2 = 0; ni2 < 2; ++ni2)
#pragma unroll
        for (int kk = 0; kk < 2; ++kk)
          acc[mi2][2 + ni2] = __builtin_amdgcn_mfma_f32_16x16x32_bf16(
              aF[mi2][kk], b1[ni2][kk], acc[mi2][2 + ni2], 0, 0, 0);
    __builtin_amdgcn_s_setprio(0);

    // p3: quad (m1,n1); stage B0(t+1)
#pragma unroll
    for (int mi2 = 0; mi2 < 4; ++mi2)
#pragma unroll
      for (int kk = 0; kk < 2; ++kk) aF[mi2][kk] = ldA(Ac, 1, mi2, kk);
    if (pre) stage_half(Bw, bn, bufn + 32768, kt + 1);
    asm volatile("s_waitcnt lgkmcnt(0)" ::: "memory");
    __builtin_amdgcn_sched_barrier(0);
    __builtin_amdgcn_s_setprio(1);
#pragma unroll
    for (int mi2 = 0; mi2 < 4; ++mi2)
#pragma unroll
      for (int ni2 = 0; ni2 < 2; ++ni2)
#pragma unroll
        for (int kk = 0; kk < 2; ++kk)
          acc[4 + mi2][2 + ni2] = __builtin_amdgcn_mfma_f32_16x16x32_bf16(
              aF[mi2][kk], b1[ni2][kk], acc[4 + mi2][2 + ni2], 0, 0, 0);
    __builtin_amdgcn_s_setprio(0);

    // p4: quad (m1,n0); stage B1(t+1)
    if (pre) stage_half(Bw, bn + 128, bufn + 49152, kt + 1);
    __builtin_amdgcn_s_setprio(1);
#pragma unroll
    for (int mi2 = 0; mi2 < 4; ++mi2)
#pragma unroll
      for (int ni2 = 0; ni2 < 2; ++ni2)
#pragma unroll
        for (int kk = 0; kk < 2; ++kk)
          acc[4 + mi2][ni2] = __builtin_amdgcn_mfma_f32_16x16x32_bf16(
              aF[mi2][kk], b0[ni2][kk], acc[4 + mi2][ni2], 0, 0, 0);
    __builtin_amdgcn_s_setprio(0);
  }

  const bool isQ = (bn < 2048);
#pragma unroll
  for (int mi = 0; mi < 8; ++mi) {
#pragma unroll
    for (int ni = 0; ni < 4; ++ni) {
      const int n = bn + wc * 64 + ni * 16 + lrow;
      const int n2 = isQ ? n : (n - 2048);
      const int h = n2 >> 6, d = n2 & 63;
#pragma unroll
      for (int r = 0; r < 4; ++r) {
        const int m = bm + wr * 128 + mi * 16 + lgrp * 4 + r;
        const int b = m >> 11, s = m & 2047;
        const size_t off = (((size_t)(b * NHEAD + h) * S_LEN + s) * HDIM) + d;
        if (isQ) Qo[off] = f2bf(acc[mi][ni][r] * qscale);
        else     Ko[off] = f2bf(acc[mi][ni][r]);
      }
    }
  }
}

// ---------------- NT GEMM v8: 128^2, BK=64, 2-buf, 1 barrier/tile ---------
// gemm_qk v7 recipe at 128^2 / 4 waves: single vmcnt(0)+barrier per BK=64
// tile (publish + retire); 2 phases {8 ds_read (kk) || stage half(t+1) ->
// lgkmcnt(0) -> 16 MFMA}. 64KB LDS, 2 blocks/CU.
// MODE 1: store bf16 [B,NH,HD,S] from m=(h,d), n=(b,s)
// MODE 2: store fp32 row-major [M][N]
template<int MODE>
__global__ __launch_bounds__(256, 2) void gemm_nt(
    const uint16_t* __restrict__ A, const uint16_t* __restrict__ B,
    void* __restrict__ C, int M, int N, int K, float scale) {
  __shared__ __align__(16) char smem[2][32768];  // [buf][A 16KB | B 16KB]

  const int t = threadIdx.x;
  const int lane = t & 63, w = t >> 6;
  const int lrow = lane & 15, lgrp = lane >> 4;
  const int bm = blockIdx.y * 128, bn = blockIdx.x * 128;
  const int wm = (w >> 1) * 64, wn = (w & 1) * 64;
  const int NT = K / 64;

  const f32x4 zero4 = {0.f, 0.f, 0.f, 0.f};
  f32x4 acc[4][4];
#pragma unroll
  for (int mi = 0; mi < 4; ++mi)
#pragma unroll
    for (int ni = 0; ni < 4; ++ni) acc[mi][ni] = zero4;

  // stage 128 rows x 64 cols (16KB, 4 loads/thread), chunk^(row&7) swizzle
  auto stage_mat = [&](const uint16_t* __restrict__ G, int grow0,
                       char* dst, int kt) {
#pragma unroll
    for (int j = 0; j < 4; ++j) {
      const int s = t + j * 256;
      const int lr = s >> 3;
      const int sc = (s & 7) ^ (lr & 7);
      load_lds16(G + (size_t)(grow0 + lr) * K + kt * 64 + sc * 8,
                 dst + j * 4096 + w * 1024);
    }
  };
  auto ldf = [&](const char* Mb, int base, int i, int kk) -> bf16x8 {
    const int row = base + i * 16 + lrow;
    const int c = kk * 4 + lgrp;
    return *(const bf16x8*)(Mb + row * 128 + ((c ^ (row & 7)) << 4));
  };

  stage_mat(A, bm, smem[0], 0);
  stage_mat(B, bn, smem[0] + 16384, 0);

  for (int kt = 0; kt < NT; ++kt) {
    char* bufc = smem[kt & 1];
    char* bufn = smem[(kt + 1) & 1];
    const bool pre = (kt + 1 < NT);

    asm volatile("s_waitcnt vmcnt(0)" ::: "memory");
    __builtin_amdgcn_s_barrier();  // publishes tile t, retires tile t-1 reads

    bf16x8 aF[4], bF[4];
    // ---- p1: kk=0 || stage A(t+1)
#pragma unroll
    for (int mi = 0; mi < 4; ++mi) aF[mi] = ldf(bufc, wm, mi, 0);
#pragma unroll
    for (int ni = 0; ni < 4; ++ni) bF[ni] = ldf(bufc + 16384, wn, ni, 0);
    if (pre) stage_mat(A, bm, bufn, kt + 1);
    asm volatile("s_waitcnt lgkmcnt(0)" ::: "memory");
    __builtin_amdgcn_sched_barrier(0);
    __builtin_amdgcn_s_setprio(1);
#pragma unroll
    for (int mi = 0; mi < 4; ++mi)
#pragma unroll
      for (int ni = 0; ni < 4; ++ni)
        acc[mi][ni] = __builtin_amdgcn_mfma_f32_16x16x32_bf16(
            aF[mi], bF[ni], acc[mi][ni], 0, 0, 0);
    __builtin_amdgcn_s_setprio(0);

    // ---- p2: kk=1 || stage B(t+1)
#pragma unroll
    for (int mi = 0; mi < 4; ++mi) aF[mi] = ldf(bufc, wm, mi, 1);
#pragma unroll
    for (int ni = 0; ni < 4; ++ni) bF[ni] = ldf(bufc + 16384, wn, ni, 1);
    if (pre) stage_mat(B, bn, bufn + 16384, kt + 1);
    asm volatile("s_waitcnt lgkmcnt(0)" ::: "memory");
    __builtin_amdgcn_sched_barrier(0);
    __builtin_amdgcn_s_setprio(1);
#pragma unroll
    for (int mi = 0; mi < 4; ++mi)
#pragma unroll
      for (int ni = 0; ni < 4; ++ni)
        acc[mi][ni] = __builtin_amdgcn_mfma_f32_16x16x32_bf16(
            aF[mi], bF[ni], acc[mi][ni], 0, 0, 0);
    __builtin_amdgcn_s_setprio(0);
  }

#pragma unroll
  for (int mi = 0; mi < 4; ++mi) {
#pragma unroll
    for (int ni = 0; ni < 4; ++ni) {
      const int n = bn + wn + ni * 16 + lrow;
#pragma unroll
      for (int r = 0; r < 4; ++r) {
        const int m = bm + wm + mi * 16 + lgrp * 4 + r;
        const float v = acc[mi][ni][r] * scale;
        if (MODE == 2) {
          ((float*)C)[(size_t)m * N + n] = v;
        } else {
          const int h = m >> 6, d = m & 63;
          const int b = n >> 11, s = n & 2047;
          ((uint16_t*)C)[(((size_t)(b * NHEAD + h) * HDIM + d) * S_LEN) + s] =
              f2bf(v);
        }
      }
    }
  }
}

// ---------------- causal flash attention v5 (r13 exact — measured best) ---
__global__ __launch_bounds__(256, 2) void attn_kernel(
    const uint16_t* __restrict__ Q, const uint16_t* __restrict__ K,
    const uint16_t* __restrict__ Vt, uint16_t* __restrict__ O) {
  extern __shared__ __align__(16) char asmem[];  // 65536
  const int t = threadIdx.x, lane = t & 63, w = t >> 6;
  const int qcol = lane & 31, hi = lane >> 5;
  const int id = blockIdx.x;
  const int bh = (id & 7) * 8 + ((id >> 3) & 7);  // 8 heads per XCD
  const int p = id >> 6;                           // 0..7
  const int b = bh >> 5, h = bh & 31;

  const uint16_t* Qbh = Q + (size_t)bh * S_LEN * HDIM;
  const uint16_t* Kbh = K + (size_t)bh * S_LEN * HDIM;
  const uint16_t* Vbh = Vt + (size_t)bh * HDIM * S_LEN;

  const int srow = lane >> 3;
  const int schunk = (lane & 7) ^ srow;

  const short one_bf = (short)0x3F80;  // bf16 1.0
  const bf16x8 onesf = {one_bf, one_bf, one_bf, one_bf,
                        one_bf, one_bf, one_bf, one_bf};

  auto Kbuf = [&](int bi, int sub) -> char* {
    return asmem + (bi * 2 + sub) * 8192;
  };
  auto Vbuf = [&](int bi, int sub) -> char* {
    return asmem + 32768 + (bi * 2 + sub) * 8192;
  };

  auto stage = [&](int k0, int bi) {
#pragma unroll
    for (int sub = 0; sub < 2; ++sub) {
      const int kb = k0 + sub * 64;
#pragma unroll
      for (int j = 0; j < 2; ++j) {
        const int r = j * 32 + w * 8 + srow;
        load_lds16(Kbh + (size_t)(kb + r) * HDIM + schunk * 8,
                   Kbuf(bi, sub) + j * 4096 + w * 1024);
        load_lds16(Vbh + (size_t)r * S_LEN + kb + schunk * 8,
                   Vbuf(bi, sub) + j * 4096 + w * 1024);
      }
    }
  };

  const int rk0 = qcol, rk1 = 32 + qcol;
  const int x0 = qcol & 7;

  for (int pass = 0; pass < 2; ++pass) {
    const int jq = pass ? (15 - p) : p;        // 128-row q-tile index
    const int qw = jq * 128 + w * 32;
    const int qg = qw + qcol;

    bf16x8 qB[4];
    {
      const uint16_t* qp = Qbh + (size_t)qg * HDIM + hi * 8;
#pragma unroll
      for (int j = 0; j < 4; ++j) qB[j] = *(const bf16x8*)(qp + 16 * j);
    }

    f32x16 oacc0, oacc1, oS;
#pragma unroll
    for (int r = 0; r < 16; ++r) { oacc0[r] = 0.f; oacc1[r] = 0.f; oS[r] = 0.f; }

    auto qk = [&](const char* Kc, f32x16& s0, f32x16& s1) {
#pragma unroll
      for (int r = 0; r < 16; ++r) { s0[r] = 0.f; s1[r] = 0.f; }
      __builtin_amdgcn_s_setprio(1);
#pragma unroll
      for (int j = 0; j < 4; ++j) {
        bf16x8 kf0 = *(const bf16x8*)(Kc + rk0 * 128 + (((2*j+hi) ^ x0) << 4));
        bf16x8 kf1 = *(const bf16x8*)(Kc + rk1 * 128 + (((2*j+hi) ^ x0) << 4));
        s0 = mfma32(kf0, qB[j], s0);
        s1 = mfma32(kf1, qB[j], s1);
      }
      __builtin_amdgcn_s_setprio(0);
    };
    auto smx = [&](int k0s, f32x16& s0, f32x16& s1) {
      if (k0s + 63 > qw) {
#pragma unroll
        for (int r = 0; r < 16; ++r) {
          const int krow = (r & 3) + 8 * (r >> 2) + 4 * hi;
          s0[r] = (k0s + krow <= qg) ? exp2_hw(s0[r]) : 0.f;
          s1[r] = (k0s + 32 + krow <= qg) ? exp2_hw(s1[r]) : 0.f;
        }
      } else {
#pragma unroll
        for (int r = 0; r < 16; ++r) {
          s0[r] = exp2_hw(s0[r]);
          s1[r] = exp2_hw(s1[r]);
        }
      }
    };
    auto repack = [&](const f32x16& s0, const f32x16& s1, bf16x8 (&paf)[4]) {
#pragma unroll
      for (int tt = 0; tt < 4; ++tt) {
        const int o = 8 * (tt & 1);
        uint32_t a0, a1, a2, a3;
        if (tt < 2) {
          a0 = cvtpk(s0[o + 0], s0[o + 1]);
          a1 = cvtpk(s0[o + 2], s0[o + 3]);
          a2 = cvtpk(s0[o + 4], s0[o + 5]);
          a3 = cvtpk(s0[o + 6], s0[o + 7]);
        } else {
          a0 = cvtpk(s1[o + 0], s1[o + 1]);
          a1 = cvtpk(s1[o + 2], s1[o + 3]);
          a2 = cvtpk(s1[o + 4], s1[o + 5]);
          a3 = cvtpk(s1[o + 6], s1[o + 7]);
        }
        plswap(a0, a2);
        plswap(a1, a3);
        union { uint32_t u[4]; bf16x8 v; } pk;
        pk.u[0] = a0; pk.u[1] = a1; pk.u[2] = a2; pk.u[3] = a3;
        paf[tt] = pk.v;
      }
    };
    auto pv = [&](const char* Vc, const bf16x8 (&paf)[4]) {
      __builtin_amdgcn_s_setprio(1);
#pragma unroll
      for (int tt = 0; tt < 4; ++tt) {
        const int c = 2 * tt + hi;
        bf16x8 v0f = *(const bf16x8*)(Vc + rk0 * 128 + ((c ^ x0) << 4));
        bf16x8 v1f = *(const bf16x8*)(Vc + rk1 * 128 + ((c ^ x0) << 4));
        oacc0 = mfma32(paf[tt], v0f, oacc0);
        oacc1 = mfma32(paf[tt], v1f, oacc1);
        oS = mfma32(paf[tt], onesf, oS);
      }
      __builtin_amdgcn_s_setprio(0);
    };

    const int nt = jq + 1;   // 128-wide kv tiles
    for (int kt = 0; kt < nt; ++kt) {
      const int cur = kt & 1;
      const int k0 = kt * 128;
      if (kt == 0) { __syncthreads(); stage(0, 0); }
      __syncthreads();                      // stage(kt) landed
      if (kt + 1 < nt) stage((kt + 1) * 128, cur ^ 1);

      const bool a1 = (k0 + 64 <= qw + 31);  // sub1 active for this wave
      f32x16 s0a, s1a, s0b, s1b;
      qk(Kbuf(cur, 0), s0a, s1a);
      if (a1) qk(Kbuf(cur, 1), s0b, s1b);    // independent of sub0 softmax
      smx(k0, s0a, s1a);
      bf16x8 paf[4];
      repack(s0a, s1a, paf);
      pv(Vbuf(cur, 0), paf);
      if (a1) {
        smx(k0 + 64, s0b, s1b);
        repack(s0b, s1b, paf);
        pv(Vbuf(cur, 1), paf);
      }
    }

#pragma unroll
    for (int r = 0; r < 16; ++r) {
      const int qrow = (r & 3) + 8 * (r >> 2) + 4 * hi;
      const float inv = 1.0f / oS[r];
      const size_t base = ((size_t)b * S_LEN + qw + qrow) * 2048 + h * 64;
      O[base + qcol] = f2bf(oacc0[r] * inv);
      O[base + 32 + qcol] = f2bf(oacc1[r] * inv);
    }
  }
}

// ---------------- launcher ----------------
extern "C" void kernel_launch(void* const* d_in, const int* in_sizes, int n_in,
                              void* d_out, int out_size, void* d_ws,
                              size_t ws_size, hipStream_t stream) {
  const float* X  = (const float*)d_in[0];
  const float* Wq = (const float*)d_in[2];
  const float* Wk = (const float*)d_in[3];
  const float* Wv = (const float*)d_in[4];
  const float* Wo = (const float*)d_in[5];
  float* out = (float*)d_out;

  char* ws = (char*)d_ws;
  uint16_t* Xbf = (uint16_t*)ws;                    // 16.78 MB [4096][2048]
  uint16_t* Wqk = (uint16_t*)(ws + 16777216);       // 16.78 MB [4096][2048]
  uint16_t* Qb  = (uint16_t*)(ws + 33554432);       // 16.78 MB [B,NH,S,HD]
  uint16_t* Kb  = (uint16_t*)(ws + 50331648);       // 16.78 MB [B,NH,S,HD]
  uint16_t* Wsm = (uint16_t*)(ws + 67108864);       //  8.39 MB (Wv bf16)
  uint16_t* Wob = (uint16_t*)(ws + 75497472);       //  8.39 MB (Wo bf16)
  uint16_t* Vtb = Wqk;   // Vt aliases Wqk (dead after QK GEMM)
  uint16_t* Ob  = Xbf;   // O aliases Xbf (dead after Vt GEMM)

  // 1/sqrt(HD) * log2(e): softmax weights computed as 2^s (v_exp_f32 direct)
  const float qscale = 0.125f * 1.4426950408889634f;

  hipFuncSetAttribute((const void*)gemm_qk,
                      hipFuncAttributeMaxDynamicSharedMemorySize, 131072);
  hipFuncSetAttribute((const void*)attn_kernel,
                      hipFuncAttributeMaxDynamicSharedMemorySize, 65536);

  conv_batch<<<24576, 256, 0, stream>>>(X, Wq, Wk, Wv, Wo, Xbf, Wqk, Wsm, Wob);
  gemm_qk<<<256, 512, 131072, stream>>>(Xbf, Wqk, Qb, Kb, qscale);
  gemm_nt<1><<<dim3(32, 16), 256, 0, stream>>>(Wsm, Xbf, Vtb, 2048, 4096, 2048, 1.0f);
  attn_kernel<<<512, 256, 65536, stream>>>(Qb, Kb, Vtb, Ob);
  gemm_nt<2><<<dim3(16, 32), 256, 0, stream>>>(Ob, Wob, out, 4096, 2048, 2048, 1.0f);
}